// Round 1
// baseline (1160.154 us; speedup 1.0000x reference)
//
#include <hip/hip_runtime.h>
#include <stdint.h>

// ---------------------------------------------------------------------------
// Wavelet window-attention, fused per 4x4 patch.
//   x: (8,64,256,256) f32; w_qkv_lh: (192,64); w_qkv_m: (384,128)
//   half-res: 128x128; windows: 64x64 per image; units = b*64+hw (512 total)
//   qkv ws layout: [unit][q(16)][t(768)][r'(2)][c2o(8)]  bf16
//     t: 0..191 low qkv | 192..575 mid | 576..767 high (path-major)
// ---------------------------------------------------------------------------

static __device__ __forceinline__ float bf2f(uint32_t v){
  union { uint32_t i; float f; } x; x.i = v << 16; return x.f;
}
static __device__ __forceinline__ uint32_t f2bf(float f){
  union { float f; uint32_t i; } x; x.f = f;
  return (x.i + 0x7FFFu + ((x.i >> 16) & 1u)) >> 16;   // RNE
}

// -------------------- weight transpose: w[t][c] -> wT[c][t] -----------------
__global__ void k_wt(const float* __restrict__ wlh, const float* __restrict__ wm,
                     float* __restrict__ wlhT, float* __restrict__ wmT){
  int i = blockIdx.x * 256 + threadIdx.x;
  if (i < 192*64){
    int t = i >> 6, c = i & 63;
    wlhT[c*192 + t] = wlh[i];
  } else if (i < 192*64 + 384*128){
    int j = i - 192*64;
    int t = j >> 7, c = j & 127;
    wmT[c*384 + t] = wm[j];
  }
}

// -------------------- K1: DWT + conv1x1 -> qkv (bf16) -----------------------
// block = 64 threads (1 wave), covers one unit row-strip quarter:
//   half-res rows {2hw,2hw+1}, half-cols [32*q4, 32*q4+32)  => 64 pixels
__global__ __launch_bounds__(64) void k_conv(const float* __restrict__ x,
    const float* __restrict__ wlhT, const float* __restrict__ wmT,
    uint16_t* __restrict__ qkv, int u0){
  __shared__ uint32_t bands[4*64*32];   // [band][c][32 words] 2 px/word, 32 KiB
  const int lane = threadIdx.x;
  const int unit = u0 + (blockIdx.x >> 2);
  const int q4   = blockIdx.x & 3;
  const int b = unit >> 6, hw = unit & 63;

  // phase 1: load x, Haar DWT, bands -> LDS bf16
  const float* xb = x + (size_t)b * 64 * 65536;
  const int col0 = q4 * 64;
  for (int it = 0; it < 32; ++it){
    int idx = it * 64 + lane;
    int j = idx & 15, rp = (idx >> 4) & 1, c = idx >> 5;
    const float* src = xb + (size_t)c * 65536 + (size_t)(4*hw + 2*rp) * 256 + col0 + 4*j;
    float4 r0 = *(const float4*)src;          // row 2*r2
    float4 r1 = *(const float4*)(src + 256);  // row 2*r2+1
    float ll0 = 0.5f*( r0.x + r0.y + r1.x + r1.y);
    float lh0 = 0.5f*(-r0.x - r0.y + r1.x + r1.y);
    float hl0 = 0.5f*(-r0.x + r0.y - r1.x + r1.y);
    float hh0 = 0.5f*( r0.x - r0.y - r1.x + r1.y);
    float ll1 = 0.5f*( r0.z + r0.w + r1.z + r1.w);
    float lh1 = 0.5f*(-r0.z - r0.w + r1.z + r1.w);
    float hl1 = 0.5f*(-r0.z + r0.w - r1.z + r1.w);
    float hh1 = 0.5f*( r0.z - r0.w - r1.z + r1.w);
    int w = rp*16 + j;
    bands[(0*64 + c)*32 + w] = f2bf(ll0) | (f2bf(ll1) << 16);
    bands[(1*64 + c)*32 + w] = f2bf(lh0) | (f2bf(lh1) << 16);
    bands[(2*64 + c)*32 + w] = f2bf(hl0) | (f2bf(hl1) << 16);
    bands[(3*64 + c)*32 + w] = f2bf(hh0) | (f2bf(hh1) << 16);
  }
  __syncthreads();

  // phase 2: conv. lane = pixel p; weights are wave-uniform scalars.
  const uint16_t* bb = (const uint16_t*)bands;  // [band][c][64 px]
  const int p = lane;
  const int rp = p >> 5, c2l = p & 31;
  const int qg = (c2l >> 3) + 4*q4;             // global q 0..15
  uint16_t* outp = qkv + ((size_t)(unit - u0) * 16 + qg) * (768*16)
                 + rp*8 + (c2l & 7);            // + t*16 per output t

  // ---- low: T=192, K=64, band 0, t base 0
  for (int tb = 0; tb < 12; ++tb){
    float2 acc[8];
    #pragma unroll
    for (int i = 0; i < 8; ++i){ acc[i].x = 0.f; acc[i].y = 0.f; }
    for (int c = 0; c < 64; ++c){
      float bv = bf2f(bb[(0*64 + c)*64 + p]);
      const float2* wr = (const float2*)(wlhT + c*192 + tb*16);
      #pragma unroll
      for (int i = 0; i < 8; ++i){ acc[i].x += wr[i].x * bv; acc[i].y += wr[i].y * bv; }
    }
    #pragma unroll
    for (int i = 0; i < 8; ++i){
      int t = tb*16 + 2*i;
      outp[(size_t)t*16]       = (uint16_t)f2bf(acc[i].x);
      outp[(size_t)(t+1)*16]   = (uint16_t)f2bf(acc[i].y);
    }
  }
  // ---- mid: T=384, K=128 (lh=band1 then hl=band2), t base 192
  for (int tb = 0; tb < 24; ++tb){
    float2 acc[8];
    #pragma unroll
    for (int i = 0; i < 8; ++i){ acc[i].x = 0.f; acc[i].y = 0.f; }
    for (int c = 0; c < 64; ++c){
      float bv = bf2f(bb[(1*64 + c)*64 + p]);
      const float2* wr = (const float2*)(wmT + c*384 + tb*16);
      #pragma unroll
      for (int i = 0; i < 8; ++i){ acc[i].x += wr[i].x * bv; acc[i].y += wr[i].y * bv; }
    }
    for (int c = 0; c < 64; ++c){
      float bv = bf2f(bb[(2*64 + c)*64 + p]);
      const float2* wr = (const float2*)(wmT + (64 + c)*384 + tb*16);
      #pragma unroll
      for (int i = 0; i < 8; ++i){ acc[i].x += wr[i].x * bv; acc[i].y += wr[i].y * bv; }
    }
    #pragma unroll
    for (int i = 0; i < 8; ++i){
      int t = 192 + tb*16 + 2*i;
      outp[(size_t)t*16]       = (uint16_t)f2bf(acc[i].x);
      outp[(size_t)(t+1)*16]   = (uint16_t)f2bf(acc[i].y);
    }
  }
  // ---- high: T=192, K=64, band 3, t base 576
  for (int tb = 0; tb < 12; ++tb){
    float2 acc[8];
    #pragma unroll
    for (int i = 0; i < 8; ++i){ acc[i].x = 0.f; acc[i].y = 0.f; }
    for (int c = 0; c < 64; ++c){
      float bv = bf2f(bb[(3*64 + c)*64 + p]);
      const float2* wr = (const float2*)(wlhT + c*192 + tb*16);
      #pragma unroll
      for (int i = 0; i < 8; ++i){ acc[i].x += wr[i].x * bv; acc[i].y += wr[i].y * bv; }
    }
    #pragma unroll
    for (int i = 0; i < 8; ++i){
      int t = 576 + tb*16 + 2*i;
      outp[(size_t)t*16]       = (uint16_t)f2bf(acc[i].x);
      outp[(size_t)(t+1)*16]   = (uint16_t)f2bf(acc[i].y);
    }
  }
}

// buf element (t, r', c2o): swizzled word = t*8 + r'*4 + (g ^ ((t>>2)&3))
static __device__ __forceinline__ float4 ld4(const uint32_t* buf, int tl, int wl){
  int s = (tl >> 2) & 3;
  uint32_t w0 = buf[tl*8 + (wl ^ s)];       // r'=0 -> s=0,1
  uint32_t w1 = buf[tl*8 + 4 + (wl ^ s)];   // r'=1 -> s=2,3
  float4 r;
  r.x = bf2f(w0 & 0xffffu); r.y = bf2f(w0 >> 16);
  r.z = bf2f(w1 & 0xffffu); r.w = bf2f(w1 >> 16);
  return r;
}

// -------------------- K2: window attention + iDWT ---------------------------
// block = 128 threads (2 waves), covers (unit, q): 4 windows (full cols q*16..+16)
__global__ __launch_bounds__(128) void k_attn(const uint16_t* __restrict__ qkv,
    float* __restrict__ out, int u0){
  __shared__ uint32_t buf[3072];      // 12 KiB: current path slab, swizzled
  __shared__ float    ybuf[4*1088];   // [wave*2+wi][ch(64)*17]: y[ch][p][s] padded
  __shared__ float    ot[64*65];      // out tile [ch][row(4)*16+col(16)] padded
  const int tid  = threadIdx.x;
  const int wv   = tid >> 6, lane = tid & 63;
  const int unit = u0 + (blockIdx.x >> 4), q = blockIdx.x & 15;
  const int b = unit >> 6, hw = unit & 63;
  const uint16_t* src = qkv + ((size_t)(unit - u0)*16 + q) * (768*16);

  for (int path = 0; path < 3; ++path){
    const int Tloc = (path == 1) ? 384 : 192;
    const int toff = (path == 0) ? 0 : (path == 1 ? 192 : 576);
    const int CH   = (path == 1) ? 128 : 64;
    const float scale = (path == 1) ? 0.17677669529663687f : 0.25f;
    __syncthreads();
    { // stage path slab global->LDS with component swizzle
      const uint4* gsrc = (const uint4*)(src + (size_t)toff * 16);
      for (int g = tid; g < Tloc*2; g += 128){
        uint4 v = gsrc[g];
        int s = (g >> 3) & 3;                    // (t>>2)&3
        uint32_t d[4] = {v.x, v.y, v.z, v.w};
        uint4 o; o.x = d[0 ^ s]; o.y = d[1 ^ s]; o.z = d[2 ^ s]; o.w = d[3 ^ s];
        ((uint4*)buf)[g] = o;
      }
    }
    __syncthreads();

    for (int wi = 0; wi < 2; ++wi){
      const int wl = wv*2 + wi;                  // window 0..3; ww = 4q+wl
      float* yw = ybuf + (wv*2 + wi) * 1088;
      if (path != 1){
        // low/high: c=16 per head; lane = (ci, dg): d split 4x4
        const int yp = (path == 0) ? 0 : 3;
        const int ci = lane >> 2, dg = lane & 3;
        for (int n = 0; n < 4; ++n){
          const int chq = 4*ci + n;
          float4 qv = ld4(buf, chq, wl);
          qv.x *= scale; qv.y *= scale; qv.z *= scale; qv.w *= scale;
          float av[4];
          #pragma unroll
          for (int dd = 0; dd < 4; ++dd){
            int chd = 4*(dg*4 + dd) + n;
            float4 kv = ld4(buf, CH + chd, wl);
            av[dd] = qv.x*kv.x + qv.y*kv.y + qv.z*kv.z + qv.w*kv.w;
          }
          float m = fmaxf(fmaxf(av[0],av[1]), fmaxf(av[2],av[3]));
          m = fmaxf(m, __shfl_xor(m, 1));
          m = fmaxf(m, __shfl_xor(m, 2));
          float e[4], sm = 0.f;
          #pragma unroll
          for (int dd = 0; dd < 4; ++dd){ e[dd] = __expf(av[dd] - m); sm += e[dd]; }
          sm += __shfl_xor(sm, 1);
          sm += __shfl_xor(sm, 2);
          float4 po; po.x = po.y = po.z = po.w = 0.f;
          #pragma unroll
          for (int dd = 0; dd < 4; ++dd){
            int chd = 4*(dg*4 + dd) + n;
            float4 vv = ld4(buf, 2*CH + chd, wl);
            po.x += e[dd]*vv.x; po.y += e[dd]*vv.y; po.z += e[dd]*vv.z; po.w += e[dd]*vv.w;
          }
          po.x += __shfl_xor(po.x,1); po.y += __shfl_xor(po.y,1);
          po.z += __shfl_xor(po.z,1); po.w += __shfl_xor(po.w,1);
          po.x += __shfl_xor(po.x,2); po.y += __shfl_xor(po.y,2);
          po.z += __shfl_xor(po.z,2); po.w += __shfl_xor(po.w,2);
          float inv = 1.f / sm;
          float myv = (dg==0) ? po.x : (dg==1) ? po.y : (dg==2) ? po.z : po.w;
          yw[chq*17 + yp*4 + dg] = myv * inv;
        }
      } else {
        // mid: c=32 per head; lane = (ci, dg): d split 2x16
        const int ci = lane >> 1, dg = lane & 1;
        for (int n = 0; n < 4; ++n){
          const int chq = 4*ci + n;
          float4 qv = ld4(buf, chq, wl);
          qv.x *= scale; qv.y *= scale; qv.z *= scale; qv.w *= scale;
          float av[16];
          #pragma unroll
          for (int dd = 0; dd < 16; ++dd){
            int chd = 4*(dg*16 + dd) + n;
            float4 kv = ld4(buf, 128 + chd, wl);
            av[dd] = qv.x*kv.x + qv.y*kv.y + qv.z*kv.z + qv.w*kv.w;
          }
          float m = av[0];
          #pragma unroll
          for (int dd = 1; dd < 16; ++dd) m = fmaxf(m, av[dd]);
          m = fmaxf(m, __shfl_xor(m, 1));
          float e[16], sm = 0.f;
          #pragma unroll
          for (int dd = 0; dd < 16; ++dd){ e[dd] = __expf(av[dd] - m); sm += e[dd]; }
          sm += __shfl_xor(sm, 1);
          float4 po; po.x = po.y = po.z = po.w = 0.f;
          #pragma unroll
          for (int dd = 0; dd < 16; ++dd){
            int chd = 4*(dg*16 + dd) + n;
            float4 vv = ld4(buf, 256 + chd, wl);
            po.x += e[dd]*vv.x; po.y += e[dd]*vv.y; po.z += e[dd]*vv.z; po.w += e[dd]*vv.w;
          }
          po.x += __shfl_xor(po.x,1); po.y += __shfl_xor(po.y,1);
          po.z += __shfl_xor(po.z,1); po.w += __shfl_xor(po.w,1);
          float inv = 1.f / sm;
          po.x *= inv; po.y *= inv; po.z *= inv; po.w *= inv;
          int yp  = 1 + (chq >> 6);       // lh2 or hl2
          int chl = chq & 63;
          float v0 = dg ? po.z : po.x;
          float v1 = dg ? po.w : po.y;
          yw[chl*17 + yp*4 + 2*dg]     = v0;
          yw[chl*17 + yp*4 + 2*dg + 1] = v1;
        }
      }
      if (path == 2){
        // iDWT for window wl -> out tile
        const int ch = lane;
        #pragma unroll
        for (int s = 0; s < 4; ++s){
          float y0 = yw[ch*17 + 0*4 + s];
          float y1 = yw[ch*17 + 1*4 + s];
          float y2 = yw[ch*17 + 2*4 + s];
          float y3 = yw[ch*17 + 3*4 + s];
          float va = 0.5f*(y0 - y1 - y2 + y3);
          float vb = 0.5f*(y0 - y1 + y2 - y3);
          float vc = 0.5f*(y0 + y1 - y2 - y3);
          float vd = 0.5f*(y0 + y1 + y2 + y3);
          int rl = 2*(s >> 1), cl = wl*4 + 2*(s & 1);
          ot[ch*65 + rl*16 + cl]         = va;
          ot[ch*65 + rl*16 + cl + 1]     = vb;
          ot[ch*65 + (rl+1)*16 + cl]     = vc;
          ot[ch*65 + (rl+1)*16 + cl + 1] = vd;
        }
      }
    }
  }
  __syncthreads();
  // coalesced output write: (ch,row) tasks, 16 floats each
  for (int task = tid; task < 256; task += 128){
    int ch = task >> 2, row = task & 3;
    const float* rp_ = ot + ch*65 + row*16;
    float* dst = out + (((size_t)b*64 + ch)*256 + (size_t)(4*hw + row))*256 + q*16;
    float4 v0 = make_float4(rp_[0],  rp_[1],  rp_[2],  rp_[3]);
    float4 v1 = make_float4(rp_[4],  rp_[5],  rp_[6],  rp_[7]);
    float4 v2 = make_float4(rp_[8],  rp_[9],  rp_[10], rp_[11]);
    float4 v3 = make_float4(rp_[12], rp_[13], rp_[14], rp_[15]);
    ((float4*)dst)[0] = v0; ((float4*)dst)[1] = v1;
    ((float4*)dst)[2] = v2; ((float4*)dst)[3] = v3;
  }
}

// ---------------------------------------------------------------------------
extern "C" void kernel_launch(void* const* d_in, const int* in_sizes, int n_in,
                              void* d_out, int out_size, void* d_ws, size_t ws_size,
                              hipStream_t stream){
  const float* x   = (const float*)d_in[0];
  const float* wlh = (const float*)d_in[1];
  const float* wm  = (const float*)d_in[2];
  float* out = (float*)d_out;

  float* wlhT = (float*)d_ws;                       // 12288 f32
  float* wmT  = wlhT + 192*64;                      // 49152 f32
  uint16_t* qkvp = (uint16_t*)((char*)d_ws + 245760);

  hipLaunchKernelGGL(k_wt, dim3(240), dim3(256), 0, stream, wlh, wm, wlhT, wmT);

  const size_t per_unit = (size_t)16 * 768 * 16 * 2;   // 393216 B
  size_t avail = (ws_size > 245760) ? ws_size - 245760 : 0;
  int U = (int)(avail / per_unit);
  if (U < 1)   U = 1;
  if (U > 512) U = 512;
  for (int u0 = 0; u0 < 512; u0 += U){
    int Uc = (512 - u0 < U) ? (512 - u0) : U;
    hipLaunchKernelGGL(k_conv, dim3(Uc*4),  dim3(64),  0, stream, x, wlhT, wmT, qkvp, u0);
    hipLaunchKernelGGL(k_attn, dim3(Uc*16), dim3(128), 0, stream, qkvp, out, u0);
  }
}

// Round 2
// 313.510 us; speedup vs baseline: 3.7005x; 3.7005x over previous
//
#include <hip/hip_runtime.h>
#include <stdint.h>

// ---------------------------------------------------------------------------
// Fully fused wavelet window-attention.
//   x: (8,64,256,256) f32; w_qkv_lh: (192,64); w_qkv_m: (384,128)
//   Block = 256 thr (4 waves) handles one (unit, quarter):
//     unit = b*64+hw (4 orig rows), quarter = 64 orig cols = 64 half-px.
//   LDS: bands[4][px64][c64] bf16 (32KB, swz by px&7; reused as y[band][ch][px]
//        swz by ch&7) + qk[tl<=384][px64] bf16 (48KB, swz by (tl>>2)&7) = 80KB.
//   Conv = MFMA 16x16x32 bf16: A=w[t][c] (global/L2), B=bands, D->qk.
// ---------------------------------------------------------------------------

typedef __attribute__((ext_vector_type(4))) float f32x4;
typedef __attribute__((ext_vector_type(8))) short bf16x8;

static __device__ __forceinline__ float bf2f(uint32_t v){
  union { uint32_t i; float f; } x; x.i = v << 16; return x.f;
}
static __device__ __forceinline__ uint32_t f2bf(float f){
  union { float f; uint32_t i; } x; x.f = f;
  return (x.i + 0x7FFFu + ((x.i >> 16) & 1u)) >> 16;   // RNE
}

// -------------------- weight cast f32 -> bf16 (layout kept [t][c]) ----------
__global__ void k_wt(const float* __restrict__ wlh, const float* __restrict__ wm,
                     uint16_t* __restrict__ wB){
  int i = blockIdx.x * 256 + threadIdx.x;
  if (i < 12288)      wB[i] = (uint16_t)f2bf(wlh[i]);
  else if (i < 61440) wB[i] = (uint16_t)f2bf(wm[i - 12288]);
}

// qk element (tl, px): byte = tl*128 + ((px*2) ^ (((tl>>2)&7)<<4))
// returns s = (r0c0, r0c1, r1c0, r1c1) for window wl (half-cols 2wl,2wl+1)
static __device__ __forceinline__ float4 ld4g(const uint32_t* qb, int tl, int wl){
  int sw = ((tl >> 2) & 7) << 2;
  uint32_t w0 = qb[tl*32 + (wl ^ sw)];
  uint32_t w1 = qb[tl*32 + ((16 + wl) ^ sw)];
  float4 r;
  r.x = bf2f(w0 & 0xffffu); r.y = bf2f(w0 >> 16);
  r.z = bf2f(w1 & 0xffffu); r.w = bf2f(w1 >> 16);
  return r;
}

template<int KS>   // KS = K/32; CH = K = 32*KS; T = 3*CH
static __device__ __forceinline__ void conv_path(const uint16_t* __restrict__ w,
    const uint16_t* __restrict__ bands, uint16_t* __restrict__ qk,
    int lane, int wv, int bbase){
  const int CH = KS * 32;
  const int nM = 6 * KS;                    // (3*CH)/16 M-tiles
  const int mrow = lane & 15, g = lane >> 4;
  const int pxb  = wv * 16 + mrow;          // this wave's N-tile column (px)
  const int swp  = (pxb & 7) << 4;
  bf16x8 bfr[KS];
  #pragma unroll
  for (int ks = 0; ks < KS; ++ks){
    int band = bbase + (ks >> 1);
    int cofs = (ks & 1) * 32;
    int e = band*4096 + pxb*64 + ((((cofs + g*8) << 1) ^ swp) >> 1);
    bfr[ks] = *(const bf16x8*)&bands[e];
  }
  for (int mt = 0; mt < nM; ++mt){
    f32x4 acc = {0.f, 0.f, 0.f, 0.f};
    #pragma unroll
    for (int ks = 0; ks < KS; ++ks){
      bf16x8 a = *(const bf16x8*)&w[(size_t)(mt*16 + mrow)*CH + ks*32 + g*8];
      acc = __builtin_amdgcn_mfma_f32_16x16x32_bf16(a, bfr[ks], acc, 0, 0, 0);
    }
    #pragma unroll
    for (int r = 0; r < 4; ++r){
      int tl = mt*16 + g*4 + r;            // D row = (lane>>4)*4 + r
      int e2 = tl*64 + (((pxb << 1) ^ (((tl >> 2) & 7) << 4)) >> 1);
      qk[e2] = (uint16_t)f2bf(acc[r]);
    }
  }
}

__global__ __launch_bounds__(256, 2) void k_fused(const float* __restrict__ x,
    const uint16_t* __restrict__ wB, float* __restrict__ out){
  __shared__ uint16_t bands[4 * 4096];   // 32 KB
  __shared__ uint16_t qk[384 * 64];      // 48 KB

  const int tid  = threadIdx.x;
  const int wv   = tid >> 6, lane = tid & 63;
  const int unit = blockIdx.x >> 2, q4 = blockIdx.x & 3;
  const int b = unit >> 6, hw = unit & 63;
  const int col0 = q4 * 64;
  const float* xb = x + (size_t)b * 64 * 65536;

  // ---------------- phase A: load x + Haar DWT -> bands -------------------
  for (int it = 0; it < 8; ++it){
    int idx = it * 256 + tid;
    int j = idx & 15, rp = (idx >> 4) & 1, c = idx >> 5;   // c: 0..63
    const float* src = xb + (size_t)c * 65536 + (size_t)(4*hw + 2*rp) * 256 + col0 + 4*j;
    float4 r0 = *(const float4*)src;
    float4 r1 = *(const float4*)(src + 256);
    float v[2][4];
    v[0][0] = 0.5f*( r0.x + r0.y + r1.x + r1.y);
    v[0][1] = 0.5f*(-r0.x - r0.y + r1.x + r1.y);
    v[0][2] = 0.5f*(-r0.x + r0.y - r1.x + r1.y);
    v[0][3] = 0.5f*( r0.x - r0.y - r1.x + r1.y);
    v[1][0] = 0.5f*( r0.z + r0.w + r1.z + r1.w);
    v[1][1] = 0.5f*(-r0.z - r0.w + r1.z + r1.w);
    v[1][2] = 0.5f*(-r0.z + r0.w - r1.z + r1.w);
    v[1][3] = 0.5f*( r0.z - r0.w - r1.z + r1.w);
    #pragma unroll
    for (int e = 0; e < 2; ++e){
      int px = rp*32 + 2*j + e;
      int off = ((c << 1) ^ ((px & 7) << 4)) >> 1;
      #pragma unroll
      for (int bb = 0; bb < 4; ++bb)
        bands[bb*4096 + px*64 + off] = (uint16_t)f2bf(v[e][bb]);
    }
  }
  __syncthreads();

  // ---------------- phases B/C: per path conv (MFMA) + attention ----------
  for (int path = 0; path < 3; ++path){
    if (path == 1) conv_path<4>(wB + 12288, bands, qk, lane, wv, 1);
    else           conv_path<2>(wB,         bands, qk, lane, wv, (path == 0) ? 0 : 3);
    __syncthreads();

    {
      const uint32_t* qb32 = (const uint32_t*)qk;
      const int CH = (path == 1) ? 128 : 64;
      const float scale = (path == 1) ? 0.17677669529663687f : 0.25f;
      for (int wi = 0; wi < 4; ++wi){
        const int wl = wv*4 + wi;
        if (path != 1){
          const int yslot = (path == 0) ? 0 : 3;
          const int ci = lane >> 2, dg = lane & 3;
          for (int n = 0; n < 4; ++n){
            const int chq = 4*ci + n;
            float4 qv = ld4g(qb32, chq, wl);
            qv.x *= scale; qv.y *= scale; qv.z *= scale; qv.w *= scale;
            float av[4];
            #pragma unroll
            for (int dd = 0; dd < 4; ++dd){
              int chd = 4*(dg*4 + dd) + n;
              float4 kv = ld4g(qb32, CH + chd, wl);
              av[dd] = qv.x*kv.x + qv.y*kv.y + qv.z*kv.z + qv.w*kv.w;
            }
            float m = fmaxf(fmaxf(av[0],av[1]), fmaxf(av[2],av[3]));
            m = fmaxf(m, __shfl_xor(m, 1));
            m = fmaxf(m, __shfl_xor(m, 2));
            float e[4], sm = 0.f;
            #pragma unroll
            for (int dd = 0; dd < 4; ++dd){ e[dd] = __expf(av[dd] - m); sm += e[dd]; }
            sm += __shfl_xor(sm, 1);
            sm += __shfl_xor(sm, 2);
            float4 po; po.x = po.y = po.z = po.w = 0.f;
            #pragma unroll
            for (int dd = 0; dd < 4; ++dd){
              int chd = 4*(dg*4 + dd) + n;
              float4 vv = ld4g(qb32, 2*CH + chd, wl);
              po.x += e[dd]*vv.x; po.y += e[dd]*vv.y; po.z += e[dd]*vv.z; po.w += e[dd]*vv.w;
            }
            po.x += __shfl_xor(po.x,1); po.y += __shfl_xor(po.y,1);
            po.z += __shfl_xor(po.z,1); po.w += __shfl_xor(po.w,1);
            po.x += __shfl_xor(po.x,2); po.y += __shfl_xor(po.y,2);
            po.z += __shfl_xor(po.z,2); po.w += __shfl_xor(po.w,2);
            float inv = 1.f / sm;
            float myv = (dg==0) ? po.x : (dg==1) ? po.y : (dg==2) ? po.z : po.w;
            int pxv = (dg >> 1)*32 + 2*wl + (dg & 1);
            int ei = yslot*4096 + chq*64 + (((pxv << 1) ^ ((chq & 7) << 4)) >> 1);
            bands[ei] = (uint16_t)f2bf(myv * inv);
          }
        } else {
          const int ci = lane >> 1, dg = lane & 1;
          for (int n = 0; n < 4; ++n){
            const int chq = 4*ci + n;            // 0..127
            float4 qv = ld4g(qb32, chq, wl);
            qv.x *= scale; qv.y *= scale; qv.z *= scale; qv.w *= scale;
            float av[16];
            #pragma unroll
            for (int dd = 0; dd < 16; ++dd){
              int chd = 4*(dg*16 + dd) + n;
              float4 kv = ld4g(qb32, 128 + chd, wl);
              av[dd] = qv.x*kv.x + qv.y*kv.y + qv.z*kv.z + qv.w*kv.w;
            }
            float m = av[0];
            #pragma unroll
            for (int dd = 1; dd < 16; ++dd) m = fmaxf(m, av[dd]);
            m = fmaxf(m, __shfl_xor(m, 1));
            float e[16], sm = 0.f;
            #pragma unroll
            for (int dd = 0; dd < 16; ++dd){ e[dd] = __expf(av[dd] - m); sm += e[dd]; }
            sm += __shfl_xor(sm, 1);
            float4 po; po.x = po.y = po.z = po.w = 0.f;
            #pragma unroll
            for (int dd = 0; dd < 16; ++dd){
              int chd = 4*(dg*16 + dd) + n;
              float4 vv = ld4g(qb32, 256 + chd, wl);
              po.x += e[dd]*vv.x; po.y += e[dd]*vv.y; po.z += e[dd]*vv.z; po.w += e[dd]*vv.w;
            }
            po.x += __shfl_xor(po.x,1); po.y += __shfl_xor(po.y,1);
            po.z += __shfl_xor(po.z,1); po.w += __shfl_xor(po.w,1);
            float inv = 1.f / sm;
            po.x *= inv; po.y *= inv; po.z *= inv; po.w *= inv;
            int yslot = 1 + (chq >> 6);
            int chl = chq & 63;
            float v0 = dg ? po.z : po.x;
            float v1 = dg ? po.w : po.y;
            uint32_t wd = f2bf(v0) | (f2bf(v1) << 16);
            int widx = (yslot*8192 + chl*128 + ((dg*64 + 4*wl) ^ ((chl & 7) << 4))) >> 2;
            ((uint32_t*)bands)[widx] = wd;
          }
        }
      }
    }
    __syncthreads();
  }

  // ---------------- phase D: iDWT + coalesced store -----------------------
  for (int it = 0; it < 4; ++it){
    int s = it * 256 + tid;                 // (ch, row, seg)
    int ch = s >> 4, row = (s >> 2) & 3, seg = s & 3;
    int base = ch*64 + ((((row >> 1)*64 + seg*16) ^ ((ch & 7) << 4)) >> 1);
    bf16x8 y0 = *(const bf16x8*)&bands[0*4096 + base];
    bf16x8 y1 = *(const bf16x8*)&bands[1*4096 + base];
    bf16x8 y2 = *(const bf16x8*)&bands[2*4096 + base];
    bf16x8 y3 = *(const bf16x8*)&bands[3*4096 + base];
    float o[16];
    #pragma unroll
    for (int p = 0; p < 8; ++p){
      float a0 = bf2f((uint16_t)y0[p]);
      float a1 = bf2f((uint16_t)y1[p]);
      float a2 = bf2f((uint16_t)y2[p]);
      float a3 = bf2f((uint16_t)y3[p]);
      float e0, e1;
      if (row & 1){ e0 = 0.5f*(a0 + a1 - a2 - a3); e1 = 0.5f*(a0 + a1 + a2 + a3); }
      else        { e0 = 0.5f*(a0 - a1 - a2 + a3); e1 = 0.5f*(a0 - a1 + a2 - a3); }
      o[2*p] = e0; o[2*p + 1] = e1;
    }
    float* dst = out + (((size_t)b*64 + ch)*256 + (size_t)(4*hw + row))*256 + col0 + seg*16;
    ((float4*)dst)[0] = make_float4(o[0], o[1], o[2], o[3]);
    ((float4*)dst)[1] = make_float4(o[4], o[5], o[6], o[7]);
    ((float4*)dst)[2] = make_float4(o[8], o[9], o[10], o[11]);
    ((float4*)dst)[3] = make_float4(o[12], o[13], o[14], o[15]);
  }
}

// ---------------------------------------------------------------------------
extern "C" void kernel_launch(void* const* d_in, const int* in_sizes, int n_in,
                              void* d_out, int out_size, void* d_ws, size_t ws_size,
                              hipStream_t stream){
  const float* x   = (const float*)d_in[0];
  const float* wlh = (const float*)d_in[1];
  const float* wm  = (const float*)d_in[2];
  float* out = (float*)d_out;
  uint16_t* wB = (uint16_t*)d_ws;          // 61440 bf16 = 122880 B

  hipLaunchKernelGGL(k_wt,    dim3(240),  dim3(256), 0, stream, wlh, wm, wB);
  hipLaunchKernelGGL(k_fused, dim3(2048), dim3(256), 0, stream, x, wB, out);
}